// Round 8
// baseline (156.982 us; speedup 1.0000x reference)
//
#include <hip/hip_runtime.h>

// BlocksparseFixedSelfAttention: B=4, T=2048, EMB=512, KBLK=64.
// R14: PROBE. Kernels = R12 (prep, 8-phase kqv, R9 heads; the 141.54us
// config). heads launched TWICE (idempotent -> bitwise-identical output),
// kqv single. dur - 141.5 ~= heads_warm + gap. Closes the ledger:
//   R10: p+k+h+3g=61.7 | R12: k+g=24.5 | R14: h+g=? -> p+g by subtraction.
// ws (MB): KQV bf16 32 @0 | xb 8 @32 | wcat bf16 2048x512 @40 | biascat @44

typedef unsigned short u16;
typedef __attribute__((ext_vector_type(8))) short short8;
typedef __attribute__((ext_vector_type(4))) float f32x4;

constexpr int TDIM  = 2048;
constexpr int EMB_D = 512;
constexpr int BB    = 4;
constexpr int NBLK  = 32;    // T / 64
constexpr int LDK   = 2048;  // KQV row stride (u16)

__device__ __forceinline__ u16 f2b(float f) {
    unsigned u = __float_as_uint(f);
    unsigned r = (u + 0x7FFFu + ((u >> 16) & 1u)) >> 16;
    return (u16)r;
}

// ---------------------------------------------------------------------------
// prep (one launch, all parts independent)
// ---------------------------------------------------------------------------
__global__ __launch_bounds__(256) void prep_k(
    const float* __restrict__ x, const float* __restrict__ Wk, const float* __restrict__ Wq,
    const float* __restrict__ Wv, const float* __restrict__ Wu,
    const float* __restrict__ bk, const float* __restrict__ bq, const float* __restrict__ bv,
    u16* __restrict__ xb, u16* __restrict__ wcat, float* __restrict__ biascat)
{
    const int bid = blockIdx.x, tid = threadIdx.x;
    if (bid < 32) {
        const int bm = (bid >> 2) * 128;   // M = 1024
        const int bn = (bid & 3) * 128;    // N = 512 (the k-dim of Wc)
        const int wid  = tid >> 6;
        const int lane = tid & 63;
        const int l15  = lane & 15;
        const int quad = lane >> 4;
        const int wm = (wid & 1) * 64;
        const int wn = (wid >> 1) * 64;

        f32x4 acc[4][4] = {};

        const float* Arow[4];
        #pragma unroll
        for (int i = 0; i < 4; ++i) {
            const int m = bm + wm + 16 * i + l15;
            Arow[i] = Wu + (size_t)(m & 511) * 1024 + (m >> 9) * 512 + quad * 8;
        }
        const float* Bcol[4];
        #pragma unroll
        for (int g = 0; g < 4; ++g)
            Bcol[g] = Wv + (bn + wn + 16 * g + l15) + (size_t)(quad * 8) * 512;

        for (int j0 = 0; j0 < 512; j0 += 32) {
            short8 a[4], b[4];
            #pragma unroll
            for (int i = 0; i < 4; ++i) {
                float4 v0 = *(const float4*)(Arow[i] + j0);
                float4 v1 = *(const float4*)(Arow[i] + j0 + 4);
                a[i] = (short8){(short)f2b(v0.x), (short)f2b(v0.y), (short)f2b(v0.z), (short)f2b(v0.w),
                                (short)f2b(v1.x), (short)f2b(v1.y), (short)f2b(v1.z), (short)f2b(v1.w)};
            }
            #pragma unroll
            for (int g = 0; g < 4; ++g) {
                const float* p = Bcol[g] + (size_t)j0 * 512;
                float v0 = p[0];          float v1 = p[512];
                float v2 = p[1024];       float v3 = p[1536];
                float v4 = p[2048];       float v5 = p[2560];
                float v6 = p[3072];       float v7 = p[3584];
                b[g] = (short8){(short)f2b(v0), (short)f2b(v1), (short)f2b(v2), (short)f2b(v3),
                                (short)f2b(v4), (short)f2b(v5), (short)f2b(v6), (short)f2b(v7)};
            }
            #pragma unroll
            for (int i = 0; i < 4; ++i)
                #pragma unroll
                for (int g = 0; g < 4; ++g)
                    acc[i][g] = __builtin_amdgcn_mfma_f32_16x16x32_bf16(a[i], b[g], acc[i][g], 0, 0, 0);
        }

        #pragma unroll
        for (int i = 0; i < 4; ++i)
            #pragma unroll
            for (int g = 0; g < 4; ++g) {
                const int col = bn + wn + 16 * g + l15;
                #pragma unroll
                for (int r = 0; r < 4; ++r) {
                    const int row = bm + wm + 16 * i + quad * 4 + r;
                    wcat[(size_t)(1024 + row) * 512 + col] = f2b(acc[i][g][r]);
                }
            }
    } else if (bid < 4640) {
        const float* src; u16* dst; int base;
        if (bid < 4128)      { src = x;  dst = xb;            base = (bid - 32) * 1024; }
        else if (bid < 4384) { src = Wk; dst = wcat;          base = (bid - 4128) * 1024; }
        else                 { src = Wq; dst = wcat + 262144; base = (bid - 4384) * 1024; }
        const int idx = base + tid * 4;
        float4 v = *(const float4*)(src + idx);
        ushort4 o = { f2b(v.x), f2b(v.y), f2b(v.z), f2b(v.w) };
        *(ushort4*)(dst + idx) = o;
    } else if (bid < 4656) {
        const int o = (bid - 4640) * 64 + (tid >> 2);
        const int p = tid & 3;
        const int n = o & 511, half = o >> 9;
        const float* wr = Wu + (size_t)n * 1024 + half * 512 + p * 128;
        const float* br = bv + p * 128;
        float s = 0.f;
        #pragma unroll
        for (int j = 0; j < 128; j += 4) {
            float4 a = *(const float4*)(wr + j);
            float4 b = *(const float4*)(br + j);
            s += a.x*b.x + a.y*b.y + a.z*b.z + a.w*b.w;
        }
        s += __shfl_xor(s, 1);
        s += __shfl_xor(s, 2);
        if (p == 0) biascat[1024 + o] = s;
    } else {
        const int idx = tid * 4;
        float4 v = (idx < 512) ? *(const float4*)(bk + idx)
                               : *(const float4*)(bq + idx - 512);
        *(float4*)(biascat + idx) = v;
    }
}

// ---------------------------------------------------------------------------
// KQV GEMM (R9 8-phase): 256x256 tile, BK=64, 512 threads (8 waves),
// 128 KiB LDS double-buffer, counted vmcnt(4), swizzled LDS reads, setprio,
// bijective XCD swizzle. Epilogue: LDS repack -> coalesced dwordx4 stores.
// ---------------------------------------------------------------------------
template<int MH, int KK>
__device__ __forceinline__ void mm16(const short8 (&a)[4], const short8 (&b)[2][4],
                                     f32x4 (&acc)[8][4])
{
    #pragma unroll
    for (int f = 0; f < 4; ++f)
        #pragma unroll
        for (int g = 0; g < 4; ++g)
            acc[MH * 4 + f][g] = __builtin_amdgcn_mfma_f32_16x16x32_bf16(
                a[f], b[KK][g], acc[MH * 4 + f][g], 0, 0, 0);
}

template<int SLOT, int MH>
__device__ __forceinline__ void lda4(short8 (&a)[4], const u16* sm, int arow, int koff)
{
    #pragma unroll
    for (int f = 0; f < 4; ++f)
        a[f] = *(const short8*)(sm + SLOT * 32768 + (arow + MH * 64 + f * 16) * 64 + koff);
}

template<int SLOT>
__device__ __forceinline__ void ldb4(short8 (&bk)[4], const u16* sm, int brow, int koff)
{
    #pragma unroll
    for (int g = 0; g < 4; ++g)
        bk[g] = *(const short8*)(sm + SLOT * 32768 + 16384 + (brow + g * 16) * 64 + koff);
}

#define STA(S, CI, T) __builtin_amdgcn_global_load_lds( \
    (const __attribute__((address_space(1))) void*)(Ag + (size_t)(CI) * 32768 + (T) * 64), \
    (__attribute__((address_space(3))) void*)(sm + (S) * 32768 + (CI) * 4096 + wid * 512), 16, 0, 0)
#define STB(S, CI, T) __builtin_amdgcn_global_load_lds( \
    (const __attribute__((address_space(1))) void*)(Bg + (size_t)(CI) * 32768 + (T) * 64), \
    (__attribute__((address_space(3))) void*)(sm + (S) * 32768 + 16384 + (CI) * 4096 + wid * 512), 16, 0, 0)
#define KBAR()  __builtin_amdgcn_s_barrier()
#define KPRIO(P) __builtin_amdgcn_s_setprio(P)
#define LGKM0() do { asm volatile("s_waitcnt lgkmcnt(0)" ::: "memory"); \
                     __builtin_amdgcn_sched_barrier(0); } while (0)
#define VMC4()  asm volatile("s_waitcnt vmcnt(4)" ::: "memory")
#define VMC0()  asm volatile("s_waitcnt vmcnt(0)" ::: "memory")

__global__ __launch_bounds__(512, 2) void kqv_gemm_k(
    const u16* __restrict__ A, const u16* __restrict__ W,
    const float* __restrict__ bias, u16* __restrict__ C)
{
    __shared__ u16 sm[65536];   // 128 KiB: [slot][A 16384 | B 16384] u16

    const int bid = blockIdx.x;
    const int wg  = (bid & 7) * 32 + (bid >> 3);   // bijective XCD swizzle (256 = 8*32)
    const int bm  = (wg & 31) * 256;               // 32 M-tiles
    const int bn  = (wg >> 5) * 256;               // 8 N-tiles (one per XCD)
    const int tid  = threadIdx.x;
    const int wid  = tid >> 6;
    const int lane = tid & 63;
    const int l15  = lane & 15;
    const int quad = lane >> 4;
    const int wm = wid >> 2;    // 0..1
    const int wn = wid & 3;     // 0..3

    const int stgrow = wid * 8 + (lane >> 3);                  // row within chunk
    const int stgk   = ((lane & 7) ^ ((lane >> 3) & 7)) << 3;  // swizzled 16B chunk
    const u16* Ag = A + (size_t)(bm + stgrow) * 512 + stgk;
    const u16* Bg = W + (size_t)(bn + stgrow) * 512 + stgk;

    const int r7     = l15 & 7;
    const int arow   = wm * 128 + l15;
    const int brow   = wn * 64 + l15;
    const int off_k0 = ((quad ^ r7) << 3);          // kf=0 swizzled 16B chunk
    const int off_k1 = (((4 | quad) ^ r7) << 3);    // kf=1

    f32x4 acc[8][4] = {};
    short8 a[4], b[2][4];

    // prologue: tile0 full (oldest 8 loads) + tile1 {a0,a2,b0,b1}
    STA(0,0,0); STA(0,2,0); STB(0,0,0); STB(0,1,0);
    STB(0,2,0); STB(0,3,0); STA(0,1,0); STA(0,3,0);
    STA(1,0,1); STA(1,2,1); STB(1,0,1); STB(1,1,1);
    VMC4(); KBAR();

    for (int it = 0; it < 3; ++it) {
        const int t = 2 * it;
        ldb4<0>(b[0], sm, brow, off_k0); lda4<0,0>(a, sm, arow, off_k0);
        STB(1,2,t+1); STB(1,3,t+1);
        KBAR(); LGKM0(); KPRIO(1); mm16<0,0>(a, b, acc); KPRIO(0); KBAR();
        ldb4<0>(b[1], sm, brow, off_k1); lda4<0,0>(a, sm, arow, off_k1);
        STA(1,1,t+1); STA(1,3,t+1);
        KBAR(); LGKM0(); KPRIO(1); mm16<0,1>(a, b, acc); KPRIO(0); KBAR();
        lda4<0,1>(a, sm, arow, off_k0);
        STA(0,0,t+2); STA(0,2,t+2);
        KBAR(); LGKM0(); KPRIO(1); mm16<1,0>(a, b, acc); KPRIO(0); KBAR();
        lda4<0,1>(a, sm, arow, off_k1);
        STB(0,0,t+2); STB(0,1,t+2);
        KBAR(); LGKM0(); KPRIO(1); mm16<1,1>(a, b, acc); KPRIO(0); VMC4(); KBAR();
        ldb4<1>(b[0], sm, brow, off_k0); lda4<1,0>(a, sm, arow, off_k0);
        STB(0,2,t+2); STB(0,3,t+2);
        KBAR(); LGKM0(); KPRIO(1); mm16<0,0>(a, b, acc); KPRIO(0); KBAR();
        ldb4<1>(b[1], sm, brow, off_k1); lda4<1,0>(a, sm, arow, off_k1);
        STA(0,1,t+2); STA(0,3,t+2);
        KBAR(); LGKM0(); KPRIO(1); mm16<0,1>(a, b, acc); KPRIO(0); KBAR();
        lda4<1,1>(a, sm, arow, off_k0);
        STA(1,0,t+3); STA(1,2,t+3);
        KBAR(); LGKM0(); KPRIO(1); mm16<1,0>(a, b, acc); KPRIO(0); KBAR();
        lda4<1,1>(a, sm, arow, off_k1);
        STB(1,0,t+3); STB(1,1,t+3);
        KBAR(); LGKM0(); KPRIO(1); mm16<1,1>(a, b, acc); KPRIO(0); VMC4(); KBAR();
    }

    ldb4<0>(b[0], sm, brow, off_k0); lda4<0,0>(a, sm, arow, off_k0);
    STB(1,2,7); STB(1,3,7);
    KBAR(); LGKM0(); KPRIO(1); mm16<0,0>(a, b, acc); KPRIO(0); KBAR();
    ldb4<0>(b[1], sm, brow, off_k1); lda4<0,0>(a, sm, arow, off_k1);
    STA(1,1,7); STA(1,3,7);
    KBAR(); LGKM0(); KPRIO(1); mm16<0,1>(a, b, acc); KPRIO(0); KBAR();
    lda4<0,1>(a, sm, arow, off_k0);
    KBAR(); LGKM0(); KPRIO(1); mm16<1,0>(a, b, acc); KPRIO(0); KBAR();
    lda4<0,1>(a, sm, arow, off_k1);
    KBAR(); LGKM0(); KPRIO(1); mm16<1,1>(a, b, acc); KPRIO(0); VMC0(); KBAR();
    ldb4<1>(b[0], sm, brow, off_k0); lda4<1,0>(a, sm, arow, off_k0);
    KBAR(); LGKM0(); KPRIO(1); mm16<0,0>(a, b, acc); KPRIO(0); KBAR();
    ldb4<1>(b[1], sm, brow, off_k1); lda4<1,0>(a, sm, arow, off_k1);
    KBAR(); LGKM0(); KPRIO(1); mm16<0,1>(a, b, acc); KPRIO(0); KBAR();
    lda4<1,1>(a, sm, arow, off_k0);
    KBAR(); LGKM0(); KPRIO(1); mm16<1,0>(a, b, acc); KPRIO(0); KBAR();
    lda4<1,1>(a, sm, arow, off_k1);
    KBAR(); LGKM0(); KPRIO(1); mm16<1,1>(a, b, acc); KPRIO(0);

    // epilogue: bias + bf16 round -> LDS [256][256] u16 -> coalesced stores
    __syncthreads();
    #pragma unroll
    for (int mf = 0; mf < 8; ++mf) {
        #pragma unroll
        for (int g = 0; g < 4; ++g) {
            const int col = wn * 64 + g * 16 + l15;
            const float bvv = bias[bn + col];
            #pragma unroll
            for (int r = 0; r < 4; ++r) {
                const int row = wm * 128 + mf * 16 + quad * 4 + r;
                sm[row * 256 + col] = f2b(acc[mf][g][r] + bvv);
            }
        }
    }
    __syncthreads();
    {
        const int rr = tid >> 5;          // 0..15
        const int ck = tid & 31;          // 0..31 (16B col chunks)
        #pragma unroll
        for (int p = 0; p < 16; ++p) {
            const int row = p * 16 + rr;
            short8 v = *(const short8*)(sm + row * 256 + ck * 8);
            *(short8*)(C + (size_t)(bm + row) * LDK + bn + ck * 8) = v;
        }
    }
}

#undef STA
#undef STB
#undef KBAR
#undef KPRIO
#undef LGKM0
#undef VMC4
#undef VMC0

// ---------------------------------------------------------------------------
// heads (R9): grid (32 blk, 4 b, 2 e-chunk), 512 threads / 8 waves.
// ---------------------------------------------------------------------------
__global__ __launch_bounds__(512) void heads_k(
    const u16* __restrict__ KQV, const float* __restrict__ bu, float* __restrict__ out)
{
    __shared__ u16 smA[64 * 104];     // [row][0:64 S1 | 64:96 S2]
    __shared__ u16 smVT[256 * 104];   // [e][0:64 VU1^T | 64:96 VU2sel^T]
    __shared__ u16 pK[2][64 * 32];    // k-panels (BK=64 = 2 x 32)
    __shared__ u16 pQ[2][64 * 32];
    __shared__ u16 pQs[2][32 * 32];

    const int blk = blockIdx.x, b = blockIdx.y;
    const int e0 = blockIdx.z * 256;
    const int tid = threadIdx.x;
    const int wid = tid >> 6, lane = tid & 63;
    const int l15 = lane & 15, quad = lane >> 4;
    const int rw = wid & 3, ch = wid >> 2;
    const size_t row0 = (size_t)b * TDIM + (size_t)blk * 64;
    const size_t brow = (size_t)b * TDIM;
    const int srow_base = 16 * rw + quad * 4;

    // ---- VU^T staging (independent of S; overlaps Phase A latency) ----
    #pragma unroll
    for (int it = 0; it < 4; ++it) {
        const int id = tid + 512 * it;         // 0..2047
        const int c  = id & 63;
        const int eo = (id >> 6) * 8;          // 0..248
        short8 v = *(const short8*)(KQV + (row0 + c) * (size_t)LDK + 1024 + e0 + eo);
        #pragma unroll
        for (int i = 0; i < 8; ++i) smVT[(eo + i) * 104 + c] = (u16)v[i];
    }
    #pragma unroll
    for (int it = 0; it < 2; ++it) {
        const int id = tid + 512 * it;         // 0..1023
        const int m  = id & 31;
        const int eo = (id >> 5) * 8;          // 0..248
        short8 v = *(const short8*)(KQV + (brow + 64 * m) * (size_t)LDK + 1536 + e0 + eo);
        #pragma unroll
        for (int i = 0; i < 8; ++i) smVT[(eo + i) * 104 + 64 + m] = (u16)v[i];
    }

    // ---- Phase A ----
    f32x4 s1[2] = {}; f32x4 s2 = {};
    const int strow  = (tid >> 2) & 63;
    const int sthalf = tid >> 8;
    const int stk    = (tid & 3) * 8;
    const u16* Kg = KQV + (row0 + strow) * (size_t)LDK + sthalf * 32 + stk;
    const u16* Qg = Kg + 512;
    const int qrow  = (tid >> 2) & 31;
    const int qhalf = (tid >> 7) & 1;
    const u16* Qsg = KQV + (brow + (size_t)64 * qrow) * (size_t)LDK + 512 + qhalf * 32 + stk;
    char* dK  = (char*)pK  + wid * 1024;
    char* dQ  = (char*)pQ  + wid * 1024;
    char* dQs = (char*)pQs + wid * 1024;   // only wid<4

    for (int k0 = 0; k0 < 512; k0 += 64) {
        __syncthreads();
        __builtin_amdgcn_global_load_lds(
            (const __attribute__((address_space(1))) void*)(Kg + k0),
            (__attribute__((address_space(3))) void*)dK, 16, 0, 0);
        __builtin_amdgcn_global_load_lds(
            (const __attribute__((address_space(1))) void*)(Qg + k0),
            (__attribute__((address_space(3))) void*)dQ, 16, 0, 0);
        if (wid < 4)
            __builtin_amdgcn_global_load_lds(
                (const __attribute__((address_space(1))) void*)(Qsg + k0),
                (__attribute__((address_space(3))) void*)dQs, 16, 0, 0);
        __syncthreads();

        short8 a0 = *(const short8*)(pK[0] + (16 * rw + l15) * 32 + quad * 8);
        short8 a1 = *(const short8*)(pK[1] + (16 * rw + l15) * 32 + quad * 8);
        #pragma unroll
        for (int jj = 0; jj < 2; ++jj) {
            const int j = 2 * ch + jj;
            short8 b0 = *(const short8*)(pQ[0] + (16 * j + l15) * 32 + quad * 8);
            short8 b1 = *(const short8*)(pQ[1] + (16 * j + l15) * 32 + quad * 8);
            s1[jj] = __builtin_amdgcn_mfma_f32_16x16x32_bf16(a0, b0, s1[jj], 0, 0, 0);
            s1[jj] = __builtin_amdgcn_mfma_f32_16x16x32_bf16(a1, b1, s1[jj], 0, 0, 0);
        }
        {
            short8 b0 = *(const short8*)(pQs[0] + (16 * ch + l15) * 32 + quad * 8);
            short8 b1 = *(const short8*)(pQs[1] + (16 * ch + l15) * 32 + quad * 8);
            s2 = __builtin_amdgcn_mfma_f32_16x16x32_bf16(a0, b0, s2, 0, 0, 0);
            s2 = __builtin_amdgcn_mfma_f32_16x16x32_bf16(a1, b1, s2, 0, 0, 0);
        }
    }

    #pragma unroll
    for (int jj = 0; jj < 2; ++jj)
        #pragma unroll
        for (int r = 0; r < 4; ++r) {
            const int rr = srow_base + r;
            const int cc = 32 * ch + 16 * jj + l15;
            smA[rr * 104 + cc] = f2b((cc <= rr) ? s1[jj][r] : 0.0f);
        }
    #pragma unroll
    for (int r = 0; r < 4; ++r) {
        const int m  = 16 * ch + l15;
        const int rr = srow_base + r;
        smA[rr * 104 + 64 + m] = f2b((m <= blk) ? s2[r] : 0.0f);
    }
    __syncthreads();

    // ---- Phase B: out = [S1|S2] @ smVT^T  (K=96, N=256) ----
    f32x4 o[8] = {};
    const u16* arow = smA + (16 * rw + l15) * 104;
    #pragma unroll
    for (int ks = 0; ks < 3; ++ks) {
        short8 as = *(const short8*)(arow + 32 * ks + quad * 8);
        #pragma unroll
        for (int nt = 0; nt < 8; ++nt) {
            short8 bs = *(const short8*)(smVT + (16 * (8 * ch + nt) + l15) * 104 + 32 * ks + quad * 8);
            o[nt] = __builtin_amdgcn_mfma_f32_16x16x32_bf16(as, bs, o[nt], 0, 0, 0);
        }
    }
    #pragma unroll
    for (int nt = 0; nt < 8; ++nt) {
        const int col = e0 + 16 * (8 * ch + nt) + l15;
        const float bvv = bu[col];
        #pragma unroll
        for (int r = 0; r < 4; ++r)
            out[(row0 + srow_base + r) * (size_t)EMB_D + col] = o[nt][r] + bvv;
    }
}

extern "C" void kernel_launch(void* const* d_in, const int* in_sizes, int n_in,
                              void* d_out, int out_size, void* d_ws, size_t ws_size,
                              hipStream_t stream)
{
    const float* x  = (const float*)d_in[0];
    const float* Wk = (const float*)d_in[1];
    const float* bk = (const float*)d_in[2];
    const float* Wq = (const float*)d_in[3];
    const float* bq = (const float*)d_in[4];
    const float* Wv = (const float*)d_in[5];
    const float* bv = (const float*)d_in[6];
    const float* Wu = (const float*)d_in[7];
    const float* bu = (const float*)d_in[8];
    float* out = (float*)d_out;

    char* w = (char*)d_ws;
    u16*   KQV     = (u16*)  (w + ((size_t)0  << 20));
    u16*   xb      = (u16*)  (w + ((size_t)32 << 20));
    u16*   wcat    = (u16*)  (w + ((size_t)40 << 20));
    float* biascat = (float*)(w + ((size_t)44 << 20));

    hipLaunchKernelGGL(prep_k, dim3(4657), dim3(256), 0, stream,
                       x, Wk, Wq, Wv, Wu, bk, bq, bv, xb, wcat, biascat);
    hipLaunchKernelGGL(kqv_gemm_k, dim3(256), dim3(512), 0, stream, xb, wcat, biascat, KQV);
    // R14 probe: heads launched twice (idempotent). dur - 141.5 ~= heads + gap.
    hipLaunchKernelGGL(heads_k, dim3(NBLK, BB, 2), dim3(512), 0, stream, KQV, bu, out);
    hipLaunchKernelGGL(heads_k, dim3(NBLK, BB, 2), dim3(512), 0, stream, KQV, bu, out);
}

// Round 9
// 142.000 us; speedup vs baseline: 1.1055x; 1.1055x over previous
//
#include <hip/hip_runtime.h>

// BlocksparseFixedSelfAttention: B=4, T=2048, EMB=512, KBLK=64.
// R15: traffic-reduction round (ledger: prep~20 kqv~23 heads~14, all ~2.5x
// bottom-up models -> BW-pressure theory).
//  - kqv: swizzle remap bm=(wg>>3)*256, bn=(wg&7)*256 -> each XCD's working
//    set = 1MB xb + 2MB wcat < 4MB L2 -> all panel re-reads L2-resident
//    (was: full 8MB xb streamed from L3 per XCD).
//  - prep: cast blocks 4096->512 (8 float4/thread, 8-deep ILP, same traffic).
// heads = R9 (unchanged). All math bitwise-identical.
// ws (MB): KQV bf16 32 @0 | xb 8 @32 | wcat bf16 2048x512 @40 | biascat @44

typedef unsigned short u16;
typedef __attribute__((ext_vector_type(8))) short short8;
typedef __attribute__((ext_vector_type(4))) float f32x4;

constexpr int TDIM  = 2048;
constexpr int EMB_D = 512;
constexpr int BB    = 4;
constexpr int NBLK  = 32;    // T / 64
constexpr int LDK   = 2048;  // KQV row stride (u16)

__device__ __forceinline__ u16 f2b(float f) {
    unsigned u = __float_as_uint(f);
    unsigned r = (u + 0x7FFFu + ((u >> 16) & 1u)) >> 16;
    return (u16)r;
}

// ---------------------------------------------------------------------------
// prep (one launch, all parts independent):
//  [0,32)    Wc MFMA blocks: wcat rows 1024+m = Wu2 @ Wv (fp32 src, f2b in-reg)
//  [32,544)  cast x -> xb          (512 blocks x 32KB, 8 float4/thread)
//  [544,576) cast Wk -> wcat[0:512]   (32 blocks x 32KB)
//  [576,608) cast Wq -> wcat[512:1024]
//  [608,624) biascat[1024+o] = Wu[o&511][.] . bv  (4 lanes/output + shfl)
//  624       biascat[0:1024] = [bk|bq]
// ---------------------------------------------------------------------------
__global__ __launch_bounds__(256) void prep_k(
    const float* __restrict__ x, const float* __restrict__ Wk, const float* __restrict__ Wq,
    const float* __restrict__ Wv, const float* __restrict__ Wu,
    const float* __restrict__ bk, const float* __restrict__ bq, const float* __restrict__ bv,
    u16* __restrict__ xb, u16* __restrict__ wcat, float* __restrict__ biascat)
{
    const int bid = blockIdx.x, tid = threadIdx.x;
    if (bid < 32) {
        const int bm = (bid >> 2) * 128;   // M = 1024
        const int bn = (bid & 3) * 128;    // N = 512 (the k-dim of Wc)
        const int wid  = tid >> 6;
        const int lane = tid & 63;
        const int l15  = lane & 15;
        const int quad = lane >> 4;
        const int wm = (wid & 1) * 64;
        const int wn = (wid >> 1) * 64;

        f32x4 acc[4][4] = {};

        const float* Arow[4];
        #pragma unroll
        for (int i = 0; i < 4; ++i) {
            const int m = bm + wm + 16 * i + l15;
            Arow[i] = Wu + (size_t)(m & 511) * 1024 + (m >> 9) * 512 + quad * 8;
        }
        const float* Bcol[4];
        #pragma unroll
        for (int g = 0; g < 4; ++g)
            Bcol[g] = Wv + (bn + wn + 16 * g + l15) + (size_t)(quad * 8) * 512;

        for (int j0 = 0; j0 < 512; j0 += 32) {
            short8 a[4], b[4];
            #pragma unroll
            for (int i = 0; i < 4; ++i) {
                float4 v0 = *(const float4*)(Arow[i] + j0);
                float4 v1 = *(const float4*)(Arow[i] + j0 + 4);
                a[i] = (short8){(short)f2b(v0.x), (short)f2b(v0.y), (short)f2b(v0.z), (short)f2b(v0.w),
                                (short)f2b(v1.x), (short)f2b(v1.y), (short)f2b(v1.z), (short)f2b(v1.w)};
            }
            #pragma unroll
            for (int g = 0; g < 4; ++g) {
                const float* p = Bcol[g] + (size_t)j0 * 512;
                float v0 = p[0];          float v1 = p[512];
                float v2 = p[1024];       float v3 = p[1536];
                float v4 = p[2048];       float v5 = p[2560];
                float v6 = p[3072];       float v7 = p[3584];
                b[g] = (short8){(short)f2b(v0), (short)f2b(v1), (short)f2b(v2), (short)f2b(v3),
                                (short)f2b(v4), (short)f2b(v5), (short)f2b(v6), (short)f2b(v7)};
            }
            #pragma unroll
            for (int i = 0; i < 4; ++i)
                #pragma unroll
                for (int g = 0; g < 4; ++g)
                    acc[i][g] = __builtin_amdgcn_mfma_f32_16x16x32_bf16(a[i], b[g], acc[i][g], 0, 0, 0);
        }

        #pragma unroll
        for (int i = 0; i < 4; ++i)
            #pragma unroll
            for (int g = 0; g < 4; ++g) {
                const int col = bn + wn + 16 * g + l15;
                #pragma unroll
                for (int r = 0; r < 4; ++r) {
                    const int row = bm + wm + 16 * i + quad * 4 + r;
                    wcat[(size_t)(1024 + row) * 512 + col] = f2b(acc[i][g][r]);
                }
            }
    } else if (bid < 608) {
        const float* src; u16* dst; int base;
        if (bid < 544)      { src = x;  dst = xb;            base = (bid - 32) * 8192; }
        else if (bid < 576) { src = Wk; dst = wcat;          base = (bid - 544) * 8192; }
        else                { src = Wq; dst = wcat + 262144; base = (bid - 576) * 8192; }
        // 8 independent float4 chains per thread (ILP); 32KB per block
        #pragma unroll
        for (int it = 0; it < 8; ++it) {
            const int idx = base + it * 1024 + tid * 4;
            float4 v = *(const float4*)(src + idx);
            ushort4 o = { f2b(v.x), f2b(v.y), f2b(v.z), f2b(v.w) };
            *(ushort4*)(dst + idx) = o;
        }
    } else if (bid < 624) {
        const int o = (bid - 608) * 64 + (tid >> 2);
        const int p = tid & 3;
        const int n = o & 511, half = o >> 9;
        const float* wr = Wu + (size_t)n * 1024 + half * 512 + p * 128;
        const float* br = bv + p * 128;
        float s = 0.f;
        #pragma unroll
        for (int j = 0; j < 128; j += 4) {
            float4 a = *(const float4*)(wr + j);
            float4 b = *(const float4*)(br + j);
            s += a.x*b.x + a.y*b.y + a.z*b.z + a.w*b.w;
        }
        s += __shfl_xor(s, 1);
        s += __shfl_xor(s, 2);
        if (p == 0) biascat[1024 + o] = s;
    } else {
        const int idx = tid * 4;
        float4 v = (idx < 512) ? *(const float4*)(bk + idx)
                               : *(const float4*)(bq + idx - 512);
        *(float4*)(biascat + idx) = v;
    }
}

// ---------------------------------------------------------------------------
// KQV GEMM (8-phase, R15 L2-resident swizzle): 256x256 tile, BK=64, 512 thr
// (8 waves), 128 KiB LDS double-buffer, counted vmcnt(4), swizzled LDS reads,
// setprio. bm=(wg>>3)*256, bn=(wg&7)*256: each XCD (bid%8) owns 4 bm x 8 bn
// -> working set 1MB xb + 2MB wcat fits its 4MB L2; all re-reads L2-hit.
// Epilogue: LDS repack -> coalesced dwordx4 stores.
// ---------------------------------------------------------------------------
template<int MH, int KK>
__device__ __forceinline__ void mm16(const short8 (&a)[4], const short8 (&b)[2][4],
                                     f32x4 (&acc)[8][4])
{
    #pragma unroll
    for (int f = 0; f < 4; ++f)
        #pragma unroll
        for (int g = 0; g < 4; ++g)
            acc[MH * 4 + f][g] = __builtin_amdgcn_mfma_f32_16x16x32_bf16(
                a[f], b[KK][g], acc[MH * 4 + f][g], 0, 0, 0);
}

template<int SLOT, int MH>
__device__ __forceinline__ void lda4(short8 (&a)[4], const u16* sm, int arow, int koff)
{
    #pragma unroll
    for (int f = 0; f < 4; ++f)
        a[f] = *(const short8*)(sm + SLOT * 32768 + (arow + MH * 64 + f * 16) * 64 + koff);
}

template<int SLOT>
__device__ __forceinline__ void ldb4(short8 (&bk)[4], const u16* sm, int brow, int koff)
{
    #pragma unroll
    for (int g = 0; g < 4; ++g)
        bk[g] = *(const short8*)(sm + SLOT * 32768 + 16384 + (brow + g * 16) * 64 + koff);
}

#define STA(S, CI, T) __builtin_amdgcn_global_load_lds( \
    (const __attribute__((address_space(1))) void*)(Ag + (size_t)(CI) * 32768 + (T) * 64), \
    (__attribute__((address_space(3))) void*)(sm + (S) * 32768 + (CI) * 4096 + wid * 512), 16, 0, 0)
#define STB(S, CI, T) __builtin_amdgcn_global_load_lds( \
    (const __attribute__((address_space(1))) void*)(Bg + (size_t)(CI) * 32768 + (T) * 64), \
    (__attribute__((address_space(3))) void*)(sm + (S) * 32768 + 16384 + (CI) * 4096 + wid * 512), 16, 0, 0)
#define KBAR()  __builtin_amdgcn_s_barrier()
#define KPRIO(P) __builtin_amdgcn_s_setprio(P)
#define LGKM0() do { asm volatile("s_waitcnt lgkmcnt(0)" ::: "memory"); \
                     __builtin_amdgcn_sched_barrier(0); } while (0)
#define VMC4()  asm volatile("s_waitcnt vmcnt(4)" ::: "memory")
#define VMC0()  asm volatile("s_waitcnt vmcnt(0)" ::: "memory")

__global__ __launch_bounds__(512, 2) void kqv_gemm_k(
    const u16* __restrict__ A, const u16* __restrict__ W,
    const float* __restrict__ bias, u16* __restrict__ C)
{
    __shared__ u16 sm[65536];   // 128 KiB: [slot][A 16384 | B 16384] u16

    const int bid = blockIdx.x;
    const int wg  = (bid & 7) * 32 + (bid >> 3);   // bijective (256 = 8*32)
    const int bm  = ((wg >> 3) & 31) * 256;        // R15: XCD owns 4 bm-panels
    const int bn  = (wg & 7) * 256;                //      x 8 bn-panels
    const int tid  = threadIdx.x;
    const int wid  = tid >> 6;
    const int lane = tid & 63;
    const int l15  = lane & 15;
    const int quad = lane >> 4;
    const int wm = wid >> 2;    // 0..1
    const int wn = wid & 3;     // 0..3

    const int stgrow = wid * 8 + (lane >> 3);                  // row within chunk
    const int stgk   = ((lane & 7) ^ ((lane >> 3) & 7)) << 3;  // swizzled 16B chunk
    const u16* Ag = A + (size_t)(bm + stgrow) * 512 + stgk;
    const u16* Bg = W + (size_t)(bn + stgrow) * 512 + stgk;

    const int r7     = l15 & 7;
    const int arow   = wm * 128 + l15;
    const int brow   = wn * 64 + l15;
    const int off_k0 = ((quad ^ r7) << 3);          // kf=0 swizzled 16B chunk
    const int off_k1 = (((4 | quad) ^ r7) << 3);    // kf=1

    f32x4 acc[8][4] = {};
    short8 a[4], b[2][4];

    // prologue: tile0 full (oldest 8 loads) + tile1 {a0,a2,b0,b1}
    STA(0,0,0); STA(0,2,0); STB(0,0,0); STB(0,1,0);
    STB(0,2,0); STB(0,3,0); STA(0,1,0); STA(0,3,0);
    STA(1,0,1); STA(1,2,1); STB(1,0,1); STB(1,1,1);
    VMC4(); KBAR();

    for (int it = 0; it < 3; ++it) {
        const int t = 2 * it;
        ldb4<0>(b[0], sm, brow, off_k0); lda4<0,0>(a, sm, arow, off_k0);
        STB(1,2,t+1); STB(1,3,t+1);
        KBAR(); LGKM0(); KPRIO(1); mm16<0,0>(a, b, acc); KPRIO(0); KBAR();
        ldb4<0>(b[1], sm, brow, off_k1); lda4<0,0>(a, sm, arow, off_k1);
        STA(1,1,t+1); STA(1,3,t+1);
        KBAR(); LGKM0(); KPRIO(1); mm16<0,1>(a, b, acc); KPRIO(0); KBAR();
        lda4<0,1>(a, sm, arow, off_k0);
        STA(0,0,t+2); STA(0,2,t+2);
        KBAR(); LGKM0(); KPRIO(1); mm16<1,0>(a, b, acc); KPRIO(0); KBAR();
        lda4<0,1>(a, sm, arow, off_k1);
        STB(0,0,t+2); STB(0,1,t+2);
        KBAR(); LGKM0(); KPRIO(1); mm16<1,1>(a, b, acc); KPRIO(0); VMC4(); KBAR();
        ldb4<1>(b[0], sm, brow, off_k0); lda4<1,0>(a, sm, arow, off_k0);
        STB(0,2,t+2); STB(0,3,t+2);
        KBAR(); LGKM0(); KPRIO(1); mm16<0,0>(a, b, acc); KPRIO(0); KBAR();
        ldb4<1>(b[1], sm, brow, off_k1); lda4<1,0>(a, sm, arow, off_k1);
        STA(0,1,t+2); STA(0,3,t+2);
        KBAR(); LGKM0(); KPRIO(1); mm16<0,1>(a, b, acc); KPRIO(0); KBAR();
        lda4<1,1>(a, sm, arow, off_k0);
        STA(1,0,t+3); STA(1,2,t+3);
        KBAR(); LGKM0(); KPRIO(1); mm16<1,0>(a, b, acc); KPRIO(0); KBAR();
        lda4<1,1>(a, sm, arow, off_k1);
        STB(1,0,t+3); STB(1,1,t+3);
        KBAR(); LGKM0(); KPRIO(1); mm16<1,1>(a, b, acc); KPRIO(0); VMC4(); KBAR();
    }

    ldb4<0>(b[0], sm, brow, off_k0); lda4<0,0>(a, sm, arow, off_k0);
    STB(1,2,7); STB(1,3,7);
    KBAR(); LGKM0(); KPRIO(1); mm16<0,0>(a, b, acc); KPRIO(0); KBAR();
    ldb4<0>(b[1], sm, brow, off_k1); lda4<0,0>(a, sm, arow, off_k1);
    STA(1,1,7); STA(1,3,7);
    KBAR(); LGKM0(); KPRIO(1); mm16<0,1>(a, b, acc); KPRIO(0); KBAR();
    lda4<0,1>(a, sm, arow, off_k0);
    KBAR(); LGKM0(); KPRIO(1); mm16<1,0>(a, b, acc); KPRIO(0); KBAR();
    lda4<0,1>(a, sm, arow, off_k1);
    KBAR(); LGKM0(); KPRIO(1); mm16<1,1>(a, b, acc); KPRIO(0); VMC0(); KBAR();
    ldb4<1>(b[0], sm, brow, off_k0); lda4<1,0>(a, sm, arow, off_k0);
    KBAR(); LGKM0(); KPRIO(1); mm16<0,0>(a, b, acc); KPRIO(0); KBAR();
    ldb4<1>(b[1], sm, brow, off_k1); lda4<1,0>(a, sm, arow, off_k1);
    KBAR(); LGKM0(); KPRIO(1); mm16<0,1>(a, b, acc); KPRIO(0); KBAR();
    lda4<1,1>(a, sm, arow, off_k0);
    KBAR(); LGKM0(); KPRIO(1); mm16<1,0>(a, b, acc); KPRIO(0); KBAR();
    lda4<1,1>(a, sm, arow, off_k1);
    KBAR(); LGKM0(); KPRIO(1); mm16<1,1>(a, b, acc); KPRIO(0);

    // epilogue: bias + bf16 round -> LDS [256][256] u16 -> coalesced stores
    __syncthreads();
    #pragma unroll
    for (int mf = 0; mf < 8; ++mf) {
        #pragma unroll
        for (int g = 0; g < 4; ++g) {
            const int col = wn * 64 + g * 16 + l15;
            const float bvv = bias[bn + col];
            #pragma unroll
            for (int r = 0; r < 4; ++r) {
                const int row = wm * 128 + mf * 16 + quad * 4 + r;
                sm[row * 256 + col] = f2b(acc[mf][g][r] + bvv);
            }
        }
    }
    __syncthreads();
    {
        const int rr = tid >> 5;          // 0..15
        const int ck = tid & 31;          // 0..31 (16B col chunks)
        #pragma unroll
        for (int p = 0; p < 16; ++p) {
            const int row = p * 16 + rr;
            short8 v = *(const short8*)(sm + row * 256 + ck * 8);
            *(short8*)(C + (size_t)(bm + row) * LDK + bn + ck * 8) = v;
        }
    }
}

#undef STA
#undef STB
#undef KBAR
#undef KPRIO
#undef LGKM0
#undef VMC4
#undef VMC0

// ---------------------------------------------------------------------------
// heads (R9): grid (32 blk, 4 b, 2 e-chunk), 512 threads / 8 waves.
// ---------------------------------------------------------------------------
__global__ __launch_bounds__(512) void heads_k(
    const u16* __restrict__ KQV, const float* __restrict__ bu, float* __restrict__ out)
{
    __shared__ u16 smA[64 * 104];     // [row][0:64 S1 | 64:96 S2]
    __shared__ u16 smVT[256 * 104];   // [e][0:64 VU1^T | 64:96 VU2sel^T]
    __shared__ u16 pK[2][64 * 32];    // k-panels (BK=64 = 2 x 32)
    __shared__ u16 pQ[2][64 * 32];
    __shared__ u16 pQs[2][32 * 32];

    const int blk = blockIdx.x, b = blockIdx.y;
    const int e0 = blockIdx.z * 256;
    const int tid = threadIdx.x;
    const int wid = tid >> 6, lane = tid & 63;
    const int l15 = lane & 15, quad = lane >> 4;
    const int rw = wid & 3, ch = wid >> 2;
    const size_t row0 = (size_t)b * TDIM + (size_t)blk * 64;
    const size_t brow = (size_t)b * TDIM;
    const int srow_base = 16 * rw + quad * 4;

    // ---- VU^T staging (independent of S; overlaps Phase A latency) ----
    #pragma unroll
    for (int it = 0; it < 4; ++it) {
        const int id = tid + 512 * it;         // 0..2047
        const int c  = id & 63;
        const int eo = (id >> 6) * 8;          // 0..248
        short8 v = *(const short8*)(KQV + (row0 + c) * (size_t)LDK + 1024 + e0 + eo);
        #pragma unroll
        for (int i = 0; i < 8; ++i) smVT[(eo + i) * 104 + c] = (u16)v[i];
    }
    #pragma unroll
    for (int it = 0; it < 2; ++it) {
        const int id = tid + 512 * it;         // 0..1023
        const int m  = id & 31;
        const int eo = (id >> 5) * 8;          // 0..248
        short8 v = *(const short8*)(KQV + (brow + 64 * m) * (size_t)LDK + 1536 + e0 + eo);
        #pragma unroll
        for (int i = 0; i < 8; ++i) smVT[(eo + i) * 104 + 64 + m] = (u16)v[i];
    }

    // ---- Phase A ----
    f32x4 s1[2] = {}; f32x4 s2 = {};
    const int strow  = (tid >> 2) & 63;
    const int sthalf = tid >> 8;
    const int stk    = (tid & 3) * 8;
    const u16* Kg = KQV + (row0 + strow) * (size_t)LDK + sthalf * 32 + stk;
    const u16* Qg = Kg + 512;
    const int qrow  = (tid >> 2) & 31;
    const int qhalf = (tid >> 7) & 1;
    const u16* Qsg = KQV + (brow + (size_t)64 * qrow) * (size_t)LDK + 512 + qhalf * 32 + stk;
    char* dK  = (char*)pK  + wid * 1024;
    char* dQ  = (char*)pQ  + wid * 1024;
    char* dQs = (char*)pQs + wid * 1024;   // only wid<4

    for (int k0 = 0; k0 < 512; k0 += 64) {
        __syncthreads();
        __builtin_amdgcn_global_load_lds(
            (const __attribute__((address_space(1))) void*)(Kg + k0),
            (__attribute__((address_space(3))) void*)dK, 16, 0, 0);
        __builtin_amdgcn_global_load_lds(
            (const __attribute__((address_space(1))) void*)(Qg + k0),
            (__attribute__((address_space(3))) void*)dQ, 16, 0, 0);
        if (wid < 4)
            __builtin_amdgcn_global_load_lds(
                (const __attribute__((address_space(1))) void*)(Qsg + k0),
                (__attribute__((address_space(3))) void*)dQs, 16, 0, 0);
        __syncthreads();

        short8 a0 = *(const short8*)(pK[0] + (16 * rw + l15) * 32 + quad * 8);
        short8 a1 = *(const short8*)(pK[1] + (16 * rw + l15) * 32 + quad * 8);
        #pragma unroll
        for (int jj = 0; jj < 2; ++jj) {
            const int j = 2 * ch + jj;
            short8 b0 = *(const short8*)(pQ[0] + (16 * j + l15) * 32 + quad * 8);
            short8 b1 = *(const short8*)(pQ[1] + (16 * j + l15) * 32 + quad * 8);
            s1[jj] = __builtin_amdgcn_mfma_f32_16x16x32_bf16(a0, b0, s1[jj], 0, 0, 0);
            s1[jj] = __builtin_amdgcn_mfma_f32_16x16x32_bf16(a1, b1, s1[jj], 0, 0, 0);
        }
        {
            short8 b0 = *(const short8*)(pQs[0] + (16 * ch + l15) * 32 + quad * 8);
            short8 b1 = *(const short8*)(pQs[1] + (16 * ch + l15) * 32 + quad * 8);
            s2 = __builtin_amdgcn_mfma_f32_16x16x32_bf16(a0, b0, s2, 0, 0, 0);
            s2 = __builtin_amdgcn_mfma_f32_16x16x32_bf16(a1, b1, s2, 0, 0, 0);
        }
    }

    #pragma unroll
    for (int jj = 0; jj < 2; ++jj)
        #pragma unroll
        for (int r = 0; r < 4; ++r) {
            const int rr = srow_base + r;
            const int cc = 32 * ch + 16 * jj + l15;
            smA[rr * 104 + cc] = f2b((cc <= rr) ? s1[jj][r] : 0.0f);
        }
    #pragma unroll
    for (int r = 0; r < 4; ++r) {
        const int m  = 16 * ch + l15;
        const int rr = srow_base + r;
        smA[rr * 104 + 64 + m] = f2b((m <= blk) ? s2[r] : 0.0f);
    }
    __syncthreads();

    // ---- Phase B: out = [S1|S2] @ smVT^T  (K=96, N=256) ----
    f32x4 o[8] = {};
    const u16* arow = smA + (16 * rw + l15) * 104;
    #pragma unroll
    for (int ks = 0; ks < 3; ++ks) {
        short8 as = *(const short8*)(arow + 32 * ks + quad * 8);
        #pragma unroll
        for (int nt = 0; nt < 8; ++nt) {
            short8 bs = *(const short8*)(smVT + (16 * (8 * ch + nt) + l15) * 104 + 32 * ks + quad * 8);
            o[nt] = __builtin_amdgcn_mfma_f32_16x16x32_bf16(as, bs, o[nt], 0, 0, 0);
        }
    }
    #pragma unroll
    for (int nt = 0; nt < 8; ++nt) {
        const int col = e0 + 16 * (8 * ch + nt) + l15;
        const float bvv = bu[col];
        #pragma unroll
        for (int r = 0; r < 4; ++r)
            out[(row0 + srow_base + r) * (size_t)EMB_D + col] = o[nt][r] + bvv;
    }
}

extern "C" void kernel_launch(void* const* d_in, const int* in_sizes, int n_in,
                              void* d_out, int out_size, void* d_ws, size_t ws_size,
                              hipStream_t stream)
{
    const float* x  = (const float*)d_in[0];
    const float* Wk = (const float*)d_in[1];
    const float* bk = (const float*)d_in[2];
    const float* Wq = (const float*)d_in[3];
    const float* bq = (const float*)d_in[4];
    const float* Wv = (const float*)d_in[5];
    const float* bv = (const float*)d_in[6];
    const float* Wu = (const float*)d_in[7];
    const float* bu = (const float*)d_in[8];
    float* out = (float*)d_out;

    char* w = (char*)d_ws;
    u16*   KQV     = (u16*)  (w + ((size_t)0  << 20));
    u16*   xb      = (u16*)  (w + ((size_t)32 << 20));
    u16*   wcat    = (u16*)  (w + ((size_t)40 << 20));
    float* biascat = (float*)(w + ((size_t)44 << 20));

    hipLaunchKernelGGL(prep_k, dim3(625), dim3(256), 0, stream,
                       x, Wk, Wq, Wv, Wu, bk, bq, bv, xb, wcat, biascat);
    hipLaunchKernelGGL(kqv_gemm_k, dim3(256), dim3(512), 0, stream, xb, wcat, biascat, KQV);
    hipLaunchKernelGGL(heads_k, dim3(NBLK, BB, 2), dim3(512), 0, stream, KQV, bu, out);
}

// Round 11
// 141.311 us; speedup vs baseline: 1.1109x; 1.0049x over previous
//
#include <hip/hip_runtime.h>

// BlocksparseFixedSelfAttention: B=4, T=2048, EMB=512, KBLK=64.
// R17 = R16 resubmitted verbatim (R10 bench attempt died to container infra,
// "failed twice", no kernel verdict; audit found no hang/fault vector).
// R16: prep's Wc-GEMM blocks (bid<32) rebuilt: fp32 operands staged to
// double-buffered LDS via global_load_lds (coalesced, 8 calls/j-step),
// counted vmcnt(8), raw s_barrier, chunk-XOR swizzle both sides
// (A: ^(row&7) b128-read 2-way-free; B: ^((row>>3)<<2) quad-split 2-way).
// Replaces the 32-deep scalar column gather (latency-serial, ~20us tail on
// 32 lone blocks). f2b in-register, same j-order -> bitwise-identical.
// casts/bias = R15; kqv = R9 8-phase (best-measured swizzle); heads = R9.
// Ledger: prep~20(floor 8) kqv~23(floor 14) heads~14(floor 12) harness~84.
// ws (MB): KQV bf16 32 @0 | xb 8 @32 | wcat bf16 2048x512 @40 | biascat @44

typedef unsigned short u16;
typedef __attribute__((ext_vector_type(8))) short short8;
typedef __attribute__((ext_vector_type(4))) float f32x4;

#define HAS1 __attribute__((address_space(1)))
#define HAS3 __attribute__((address_space(3)))

constexpr int TDIM  = 2048;
constexpr int EMB_D = 512;
constexpr int BB    = 4;
constexpr int NBLK  = 32;    // T / 64
constexpr int LDK   = 2048;  // KQV row stride (u16)

__device__ __forceinline__ u16 f2b(float f) {
    unsigned u = __float_as_uint(f);
    unsigned r = (u + 0x7FFFu + ((u >> 16) & 1u)) >> 16;
    return (u16)r;
}

// ---------------------------------------------------------------------------
// prep (one launch, all parts independent):
//  [0,32)    Wc MFMA blocks (LDS-staged fp32, dbuf, counted vmcnt)
//  [32,544)  cast x -> xb          (512 blocks x 32KB, 8 float4/thread)
//  [544,576) cast Wk -> wcat[0:512]
//  [576,608) cast Wq -> wcat[512:1024]
//  [608,624) biascat[1024+o] = Wu[o&511][.] . bv
//  624       biascat[0:1024] = [bk|bq]
// ---------------------------------------------------------------------------
__global__ __launch_bounds__(256) void prep_k(
    const float* __restrict__ x, const float* __restrict__ Wk, const float* __restrict__ Wq,
    const float* __restrict__ Wv, const float* __restrict__ Wu,
    const float* __restrict__ bk, const float* __restrict__ bq, const float* __restrict__ bv,
    u16* __restrict__ xb, u16* __restrict__ wcat, float* __restrict__ biascat)
{
    __shared__ float At[2][4096];   // [buf][128 rows][32 j] fp32 (16KB each)
    __shared__ float Bt[2][4096];   // [buf][32 j][128 cols] fp32 (16KB each)

    const int bid = blockIdx.x, tid = threadIdx.x;
    if (bid < 32) {
        // Wc[m][k] = sum_j Wu2[m][j] * Wv[j][k];  Wu2[m][j] = Wu[m&511][(m>>9)*512+j]
        // 128x128 tile, BJ=32, fp32 LDS double-buffer. Same j-order as before
        // (f2b in-register on identical values) -> bitwise-equal wcat.
        const int bm = (bid >> 2) * 128;   // M = 1024
        const int bn = (bid & 3) * 128;    // N = 512 (the k-dim of Wc)
        const int wid  = tid >> 6;
        const int lane = tid & 63;
        const int l15  = lane & 15;
        const int quad = lane >> 4;
        const int wm = (wid & 1) * 64;
        const int wn = (wid >> 1) * 64;

        f32x4 acc[4][4] = {};

        // staging: 4 calls each for A and B; id = cl*256+tid.
        //  A: row=id>>3 (128 rows x 8 chunks), src chunk = (id&7) ^ (row&7)
        //  B: row=id>>5 (32 rows x 32 chunks), src chunk = (id&31) ^ ((row>>3)<<2)
#define WST(BUF, J0) do { \
    _Pragma("unroll") \
    for (int cl = 0; cl < 4; ++cl) { \
        const int idA = cl * 256 + tid; \
        const int rA  = idA >> 3; \
        const int cAx = (idA & 7) ^ (rA & 7); \
        const int mA  = bm + rA; \
        __builtin_amdgcn_global_load_lds( \
            (const HAS1 void*)(Wu + (size_t)(mA & 511) * 1024 + (mA >> 9) * 512 + (J0) + cAx * 4), \
            (HAS3 void*)((char*)At + (BUF) * 16384 + (idA & 0x3C0) * 16), 16, 0, 0); \
        const int rB  = idA >> 5; \
        const int cBx = (idA & 31) ^ ((rB >> 3) << 2); \
        __builtin_amdgcn_global_load_lds( \
            (const HAS1 void*)(Wv + (size_t)((J0) + rB) * 512 + bn + cBx * 4), \
            (HAS3 void*)((char*)Bt + (BUF) * 16384 + (idA & 0x3C0) * 16), 16, 0, 0); \
    } \
} while (0)

        WST(0, 0);
        for (int t = 0; t < 16; ++t) {
            const int buf = t & 1;
            if (t < 15) {
                WST(buf ^ 1, (t + 1) * 32);
                asm volatile("s_waitcnt vmcnt(8)" ::: "memory");
            } else {
                asm volatile("s_waitcnt vmcnt(0)" ::: "memory");
            }
            __builtin_amdgcn_s_barrier();
            __builtin_amdgcn_sched_barrier(0);

            const float* Ab = &At[buf][0];
            const float* Bb = &Bt[buf][0];
            short8 a[4], b[4];
            #pragma unroll
            for (int i = 0; i < 4; ++i) {
                const int ml = wm + 16 * i + l15;
                const float* pa = Ab + ml * 32;
                const int x0 = (((quad * 2)     ^ (ml & 7)) << 2);
                const int x1 = (((quad * 2 + 1) ^ (ml & 7)) << 2);
                float4 v0 = *(const float4*)(pa + x0);
                float4 v1 = *(const float4*)(pa + x1);
                a[i] = (short8){(short)f2b(v0.x), (short)f2b(v0.y), (short)f2b(v0.z), (short)f2b(v0.w),
                                (short)f2b(v1.x), (short)f2b(v1.y), (short)f2b(v1.z), (short)f2b(v1.w)};
            }
            #pragma unroll
            for (int g = 0; g < 4; ++g) {
                const int c  = wn + 16 * g + l15;
                const int pc = ((((c >> 2) ^ (quad << 2))) << 2) + (c & 3);
                const float* pb = Bb + quad * 8 * 128 + pc;
                float t0 = pb[0];       float t1 = pb[128];
                float t2 = pb[256];     float t3 = pb[384];
                float t4 = pb[512];     float t5 = pb[640];
                float t6 = pb[768];     float t7 = pb[896];
                b[g] = (short8){(short)f2b(t0), (short)f2b(t1), (short)f2b(t2), (short)f2b(t3),
                                (short)f2b(t4), (short)f2b(t5), (short)f2b(t6), (short)f2b(t7)};
            }
            #pragma unroll
            for (int i = 0; i < 4; ++i)
                #pragma unroll
                for (int g = 0; g < 4; ++g)
                    acc[i][g] = __builtin_amdgcn_mfma_f32_16x16x32_bf16(a[i], b[g], acc[i][g], 0, 0, 0);
            __builtin_amdgcn_s_barrier();
        }
#undef WST

        #pragma unroll
        for (int i = 0; i < 4; ++i)
            #pragma unroll
            for (int g = 0; g < 4; ++g) {
                const int col = bn + wn + 16 * g + l15;
                #pragma unroll
                for (int r = 0; r < 4; ++r) {
                    const int row = bm + wm + 16 * i + quad * 4 + r;
                    wcat[(size_t)(1024 + row) * 512 + col] = f2b(acc[i][g][r]);
                }
            }
    } else if (bid < 608) {
        const float* src; u16* dst; int base;
        if (bid < 544)      { src = x;  dst = xb;            base = (bid - 32) * 8192; }
        else if (bid < 576) { src = Wk; dst = wcat;          base = (bid - 544) * 8192; }
        else                { src = Wq; dst = wcat + 262144; base = (bid - 576) * 8192; }
        #pragma unroll
        for (int it = 0; it < 8; ++it) {
            const int idx = base + it * 1024 + tid * 4;
            float4 v = *(const float4*)(src + idx);
            ushort4 o = { f2b(v.x), f2b(v.y), f2b(v.z), f2b(v.w) };
            *(ushort4*)(dst + idx) = o;
        }
    } else if (bid < 624) {
        const int o = (bid - 608) * 64 + (tid >> 2);
        const int p = tid & 3;
        const int n = o & 511, half = o >> 9;
        const float* wr = Wu + (size_t)n * 1024 + half * 512 + p * 128;
        const float* br = bv + p * 128;
        float s = 0.f;
        #pragma unroll
        for (int j = 0; j < 128; j += 4) {
            float4 a = *(const float4*)(wr + j);
            float4 b = *(const float4*)(br + j);
            s += a.x*b.x + a.y*b.y + a.z*b.z + a.w*b.w;
        }
        s += __shfl_xor(s, 1);
        s += __shfl_xor(s, 2);
        if (p == 0) biascat[1024 + o] = s;
    } else {
        const int idx = tid * 4;
        float4 v = (idx < 512) ? *(const float4*)(bk + idx)
                               : *(const float4*)(bq + idx - 512);
        *(float4*)(biascat + idx) = v;
    }
}

// ---------------------------------------------------------------------------
// KQV GEMM (R9 8-phase, best-measured): 256x256 tile, BK=64, 512 threads,
// 128 KiB LDS double-buffer, counted vmcnt(4), swizzled LDS reads, setprio,
// bijective XCD swizzle. Epilogue: LDS repack -> coalesced dwordx4 stores.
// ---------------------------------------------------------------------------
template<int MH, int KK>
__device__ __forceinline__ void mm16(const short8 (&a)[4], const short8 (&b)[2][4],
                                     f32x4 (&acc)[8][4])
{
    #pragma unroll
    for (int f = 0; f < 4; ++f)
        #pragma unroll
        for (int g = 0; g < 4; ++g)
            acc[MH * 4 + f][g] = __builtin_amdgcn_mfma_f32_16x16x32_bf16(
                a[f], b[KK][g], acc[MH * 4 + f][g], 0, 0, 0);
}

template<int SLOT, int MH>
__device__ __forceinline__ void lda4(short8 (&a)[4], const u16* sm, int arow, int koff)
{
    #pragma unroll
    for (int f = 0; f < 4; ++f)
        a[f] = *(const short8*)(sm + SLOT * 32768 + (arow + MH * 64 + f * 16) * 64 + koff);
}

template<int SLOT>
__device__ __forceinline__ void ldb4(short8 (&bk)[4], const u16* sm, int brow, int koff)
{
    #pragma unroll
    for (int g = 0; g < 4; ++g)
        bk[g] = *(const short8*)(sm + SLOT * 32768 + 16384 + (brow + g * 16) * 64 + koff);
}

#define STA(S, CI, T) __builtin_amdgcn_global_load_lds( \
    (const HAS1 void*)(Ag + (size_t)(CI) * 32768 + (T) * 64), \
    (HAS3 void*)(sm + (S) * 32768 + (CI) * 4096 + wid * 512), 16, 0, 0)
#define STB(S, CI, T) __builtin_amdgcn_global_load_lds( \
    (const HAS1 void*)(Bg + (size_t)(CI) * 32768 + (T) * 64), \
    (HAS3 void*)(sm + (S) * 32768 + 16384 + (CI) * 4096 + wid * 512), 16, 0, 0)
#define KBAR()  __builtin_amdgcn_s_barrier()
#define KPRIO(P) __builtin_amdgcn_s_setprio(P)
#define LGKM0() do { asm volatile("s_waitcnt lgkmcnt(0)" ::: "memory"); \
                     __builtin_amdgcn_sched_barrier(0); } while (0)
#define VMC4()  asm volatile("s_waitcnt vmcnt(4)" ::: "memory")
#define VMC0()  asm volatile("s_waitcnt vmcnt(0)" ::: "memory")

__global__ __launch_bounds__(512, 2) void kqv_gemm_k(
    const u16* __restrict__ A, const u16* __restrict__ W,
    const float* __restrict__ bias, u16* __restrict__ C)
{
    __shared__ u16 sm[65536];   // 128 KiB: [slot][A 16384 | B 16384] u16

    const int bid = blockIdx.x;
    const int wg  = (bid & 7) * 32 + (bid >> 3);   // bijective XCD swizzle (256 = 8*32)
    const int bm  = (wg & 31) * 256;               // 32 M-tiles
    const int bn  = (wg >> 5) * 256;               // 8 N-tiles (one per XCD)
    const int tid  = threadIdx.x;
    const int wid  = tid >> 6;
    const int lane = tid & 63;
    const int l15  = lane & 15;
    const int quad = lane >> 4;
    const int wm = wid >> 2;    // 0..1
    const int wn = wid & 3;     // 0..3

    const int stgrow = wid * 8 + (lane >> 3);                  // row within chunk
    const int stgk   = ((lane & 7) ^ ((lane >> 3) & 7)) << 3;  // swizzled 16B chunk
    const u16* Ag = A + (size_t)(bm + stgrow) * 512 + stgk;
    const u16* Bg = W + (size_t)(bn + stgrow) * 512 + stgk;

    const int r7     = l15 & 7;
    const int arow   = wm * 128 + l15;
    const int brow   = wn * 64 + l15;
    const int off_k0 = ((quad ^ r7) << 3);          // kf=0 swizzled 16B chunk
    const int off_k1 = (((4 | quad) ^ r7) << 3);    // kf=1

    f32x4 acc[8][4] = {};
    short8 a[4], b[2][4];

    // prologue: tile0 full (oldest 8 loads) + tile1 {a0,a2,b0,b1}
    STA(0,0,0); STA(0,2,0); STB(0,0,0); STB(0,1,0);
    STB(0,2,0); STB(0,3,0); STA(0,1,0); STA(0,3,0);
    STA(1,0,1); STA(1,2,1); STB(1,0,1); STB(1,1,1);
    VMC4(); KBAR();

    for (int it = 0; it < 3; ++it) {
        const int t = 2 * it;
        ldb4<0>(b[0], sm, brow, off_k0); lda4<0,0>(a, sm, arow, off_k0);
        STB(1,2,t+1); STB(1,3,t+1);
        KBAR(); LGKM0(); KPRIO(1); mm16<0,0>(a, b, acc); KPRIO(0); KBAR();
        ldb4<0>(b[1], sm, brow, off_k1); lda4<0,0>(a, sm, arow, off_k1);
        STA(1,1,t+1); STA(1,3,t+1);
        KBAR(); LGKM0(); KPRIO(1); mm16<0,1>(a, b, acc); KPRIO(0); KBAR();
        lda4<0,1>(a, sm, arow, off_k0);
        STA(0,0,t+2); STA(0,2,t+2);
        KBAR(); LGKM0(); KPRIO(1); mm16<1,0>(a, b, acc); KPRIO(0); KBAR();
        lda4<0,1>(a, sm, arow, off_k1);
        STB(0,0,t+2); STB(0,1,t+2);
        KBAR(); LGKM0(); KPRIO(1); mm16<1,1>(a, b, acc); KPRIO(0); VMC4(); KBAR();
        ldb4<1>(b[0], sm, brow, off_k0); lda4<1,0>(a, sm, arow, off_k0);
        STB(0,2,t+2); STB(0,3,t+2);
        KBAR(); LGKM0(); KPRIO(1); mm16<0,0>(a, b, acc); KPRIO(0); KBAR();
        ldb4<1>(b[1], sm, brow, off_k1); lda4<1,0>(a, sm, arow, off_k1);
        STA(0,1,t+2); STA(0,3,t+2);
        KBAR(); LGKM0(); KPRIO(1); mm16<0,1>(a, b, acc); KPRIO(0); KBAR();
        lda4<1,1>(a, sm, arow, off_k0);
        STA(1,0,t+3); STA(1,2,t+3);
        KBAR(); LGKM0(); KPRIO(1); mm16<1,0>(a, b, acc); KPRIO(0); KBAR();
        lda4<1,1>(a, sm, arow, off_k1);
        STB(1,0,t+3); STB(1,1,t+3);
        KBAR(); LGKM0(); KPRIO(1); mm16<1,1>(a, b, acc); KPRIO(0); VMC4(); KBAR();
    }

    ldb4<0>(b[0], sm, brow, off_k0); lda4<0,0>(a, sm, arow, off_k0);
    STB(1,2,7); STB(1,3,7);
    KBAR(); LGKM0(); KPRIO(1); mm16<0,0>(a, b, acc); KPRIO(0); KBAR();
    ldb4<0>(b[1], sm, brow, off_k1); lda4<0,0>(a, sm, arow, off_k1);
    STA(1,1,7); STA(1,3,7);
    KBAR(); LGKM0(); KPRIO(1); mm16<0,1>(a, b, acc); KPRIO(0); KBAR();
    lda4<0,1>(a, sm, arow, off_k0);
    KBAR(); LGKM0(); KPRIO(1); mm16<1,0>(a, b, acc); KPRIO(0); KBAR();
    lda4<0,1>(a, sm, arow, off_k1);
    KBAR(); LGKM0(); KPRIO(1); mm16<1,1>(a, b, acc); KPRIO(0); VMC0(); KBAR();
    ldb4<1>(b[0], sm, brow, off_k0); lda4<1,0>(a, sm, arow, off_k0);
    KBAR(); LGKM0(); KPRIO(1); mm16<0,0>(a, b, acc); KPRIO(0); KBAR();
    ldb4<1>(b[1], sm, brow, off_k1); lda4<1,0>(a, sm, arow, off_k1);
    KBAR(); LGKM0(); KPRIO(1); mm16<0,1>(a, b, acc); KPRIO(0); KBAR();
    lda4<1,1>(a, sm, arow, off_k0);
    KBAR(); LGKM0(); KPRIO(1); mm16<1,0>(a, b, acc); KPRIO(0); KBAR();
    lda4<1,1>(a, sm, arow, off_k1);
    KBAR(); LGKM0(); KPRIO(1); mm16<1,1>(a, b, acc); KPRIO(0);

    // epilogue: bias + bf16 round -> LDS [256][256] u16 -> coalesced stores
    __syncthreads();
    #pragma unroll
    for (int mf = 0; mf < 8; ++mf) {
        #pragma unroll
        for (int g = 0; g < 4; ++g) {
            const int col = wn * 64 + g * 16 + l15;
            const float bvv = bias[bn + col];
            #pragma unroll
            for (int r = 0; r < 4; ++r) {
                const int row = wm * 128 + mf * 16 + quad * 4 + r;
                sm[row * 256 + col] = f2b(acc[mf][g][r] + bvv);
            }
        }
    }
    __syncthreads();
    {
        const int rr = tid >> 5;          // 0..15
        const int ck = tid & 31;          // 0..31 (16B col chunks)
        #pragma unroll
        for (int p = 0; p < 16; ++p) {
            const int row = p * 16 + rr;
            short8 v = *(const short8*)(sm + row * 256 + ck * 8);
            *(short8*)(C + (size_t)(bm + row) * LDK + bn + ck * 8) = v;
        }
    }
}

#undef STA
#undef STB
#undef KBAR
#undef KPRIO
#undef LGKM0
#undef VMC4
#undef VMC0

// ---------------------------------------------------------------------------
// heads (R9): grid (32 blk, 4 b, 2 e-chunk), 512 threads / 8 waves.
// ---------------------------------------------------------------------------
__global__ __launch_bounds__(512) void heads_k(
    const u16* __restrict__ KQV, const float* __restrict__ bu, float* __restrict__ out)
{
    __shared__ u16 smA[64 * 104];     // [row][0:64 S1 | 64:96 S2]
    __shared__ u16 smVT[256 * 104];   // [e][0:64 VU1^T | 64:96 VU2sel^T]
    __shared__ u16 pK[2][64 * 32];    // k-panels (BK=64 = 2 x 32)
    __shared__ u16 pQ[2][64 * 32];
    __shared__ u16 pQs[2][32 * 32];

    const int blk = blockIdx.x, b = blockIdx.y;
    const int e0 = blockIdx.z * 256;
    const int tid = threadIdx.x;
    const int wid = tid >> 6, lane = tid & 63;
    const int l15 = lane & 15, quad = lane >> 4;
    const int rw = wid & 3, ch = wid >> 2;
    const size_t row0 = (size_t)b * TDIM + (size_t)blk * 64;
    const size_t brow = (size_t)b * TDIM;
    const int srow_base = 16 * rw + quad * 4;

    // ---- VU^T staging (independent of S; overlaps Phase A latency) ----
    #pragma unroll
    for (int it = 0; it < 4; ++it) {
        const int id = tid + 512 * it;         // 0..2047
        const int c  = id & 63;
        const int eo = (id >> 6) * 8;          // 0..248
        short8 v = *(const short8*)(KQV + (row0 + c) * (size_t)LDK + 1024 + e0 + eo);
        #pragma unroll
        for (int i = 0; i < 8; ++i) smVT[(eo + i) * 104 + c] = (u16)v[i];
    }
    #pragma unroll
    for (int it = 0; it < 2; ++it) {
        const int id = tid + 512 * it;         // 0..1023
        const int m  = id & 31;
        const int eo = (id >> 5) * 8;          // 0..248
        short8 v = *(const short8*)(KQV + (brow + 64 * m) * (size_t)LDK + 1536 + e0 + eo);
        #pragma unroll
        for (int i = 0; i < 8; ++i) smVT[(eo + i) * 104 + 64 + m] = (u16)v[i];
    }

    // ---- Phase A ----
    f32x4 s1[2] = {}; f32x4 s2 = {};
    const int strow  = (tid >> 2) & 63;
    const int sthalf = tid >> 8;
    const int stk    = (tid & 3) * 8;
    const u16* Kg = KQV + (row0 + strow) * (size_t)LDK + sthalf * 32 + stk;
    const u16* Qg = Kg + 512;
    const int qrow  = (tid >> 2) & 31;
    const int qhalf = (tid >> 7) & 1;
    const u16* Qsg = KQV + (brow + (size_t)64 * qrow) * (size_t)LDK + 512 + qhalf * 32 + stk;
    char* dK  = (char*)pK  + wid * 1024;
    char* dQ  = (char*)pQ  + wid * 1024;
    char* dQs = (char*)pQs + wid * 1024;   // only wid<4

    for (int k0 = 0; k0 < 512; k0 += 64) {
        __syncthreads();
        __builtin_amdgcn_global_load_lds(
            (const HAS1 void*)(Kg + k0),
            (HAS3 void*)dK, 16, 0, 0);
        __builtin_amdgcn_global_load_lds(
            (const HAS1 void*)(Qg + k0),
            (HAS3 void*)dQ, 16, 0, 0);
        if (wid < 4)
            __builtin_amdgcn_global_load_lds(
                (const HAS1 void*)(Qsg + k0),
                (HAS3 void*)dQs, 16, 0, 0);
        __syncthreads();

        short8 a0 = *(const short8*)(pK[0] + (16 * rw + l15) * 32 + quad * 8);
        short8 a1 = *(const short8*)(pK[1] + (16 * rw + l15) * 32 + quad * 8);
        #pragma unroll
        for (int jj = 0; jj < 2; ++jj) {
            const int j = 2 * ch + jj;
            short8 b0 = *(const short8*)(pQ[0] + (16 * j + l15) * 32 + quad * 8);
            short8 b1 = *(const short8*)(pQ[1] + (16 * j + l15) * 32 + quad * 8);
            s1[jj] = __builtin_amdgcn_mfma_f32_16x16x32_bf16(a0, b0, s1[jj], 0, 0, 0);
            s1[jj] = __builtin_amdgcn_mfma_f32_16x16x32_bf16(a1, b1, s1[jj], 0, 0, 0);
        }
        {
            short8 b0 = *(const short8*)(pQs[0] + (16 * ch + l15) * 32 + quad * 8);
            short8 b1 = *(const short8*)(pQs[1] + (16 * ch + l15) * 32 + quad * 8);
            s2 = __builtin_amdgcn_mfma_f32_16x16x32_bf16(a0, b0, s2, 0, 0, 0);
            s2 = __builtin_amdgcn_mfma_f32_16x16x32_bf16(a1, b1, s2, 0, 0, 0);
        }
    }

    #pragma unroll
    for (int jj = 0; jj < 2; ++jj)
        #pragma unroll
        for (int r = 0; r < 4; ++r) {
            const int rr = srow_base + r;
            const int cc = 32 * ch + 16 * jj + l15;
            smA[rr * 104 + cc] = f2b((cc <= rr) ? s1[jj][r] : 0.0f);
        }
    #pragma unroll
    for (int r = 0; r < 4; ++r) {
        const int m  = 16 * ch + l15;
        const int rr = srow_base + r;
        smA[rr * 104 + 64 + m] = f2b((m <= blk) ? s2[r] : 0.0f);
    }
    __syncthreads();

    // ---- Phase B: out = [S1|S2] @ smVT^T  (K=96, N=256) ----
    f32x4 o[8] = {};
    const u16* arow = smA + (16 * rw + l15) * 104;
    #pragma unroll
    for (int ks = 0; ks < 3; ++ks) {
        short8 as = *(const short8*)(arow + 32 * ks + quad * 8);
        #pragma unroll
        for (int nt = 0; nt < 8; ++nt) {
            short8 bs = *(const short8*)(smVT + (16 * (8 * ch + nt) + l15) * 104 + 32 * ks + quad * 8);
            o[nt] = __builtin_amdgcn_mfma_f32_16x16x32_bf16(as, bs, o[nt], 0, 0, 0);
        }
    }
    #pragma unroll
    for (int nt = 0; nt < 8; ++nt) {
        const int col = e0 + 16 * (8 * ch + nt) + l15;
        const float bvv = bu[col];
        #pragma unroll
        for (int r = 0; r < 4; ++r)
            out[(row0 + srow_base + r) * (size_t)EMB_D + col] = o[nt][r] + bvv;
    }
}

extern "C" void kernel_launch(void* const* d_in, const int* in_sizes, int n_in,
                              void* d_out, int out_size, void* d_ws, size_t ws_size,
                              hipStream_t stream)
{
    const float* x  = (const float*)d_in[0];
    const float* Wk = (const float*)d_in[1];
    const float* bk = (const float*)d_in[2];
    const float* Wq = (const float*)d_in[3];
    const float* bq = (const float*)d_in[4];
    const float* Wv = (const float*)d_in[5];
    const float* bv = (const float*)d_in[6];
    const float* Wu = (const float*)d_in[7];
    const float* bu = (const float*)d_in[8];
    float* out = (float*)d_out;

    char* w = (char*)d_ws;
    u16*   KQV     = (u16*)  (w + ((size_t)0  << 20));
    u16*   xb      = (u16*)  (w + ((size_t)32 << 20));
    u16*   wcat    = (u16*)  (w + ((size_t)40 << 20));
    float* biascat = (float*)(w + ((size_t)44 << 20));

    hipLaunchKernelGGL(prep_k, dim3(625), dim3(256), 0, stream,
                       x, Wk, Wq, Wv, Wu, bk, bq, bv, xb, wcat, biascat);
    hipLaunchKernelGGL(kqv_gemm_k, dim3(256), dim3(512), 0, stream, xb, wcat, biascat, KQV);
    hipLaunchKernelGGL(heads_k, dim3(NBLK, BB, 2), dim3(512), 0, stream, KQV, bu, out);
}